// Round 8
// baseline (230.031 us; speedup 1.0000x reference)
//
#include <hip/hip_runtime.h>
#include <hip/hip_bf16.h>

typedef _Float16 f16x8 __attribute__((ext_vector_type(8)));
typedef float f32x4 __attribute__((ext_vector_type(4)));

#define N_ROWS 4096
#define F_DIM 64
#define EMPF 0.1f
#define EMPD 0.1
#define ZEROV 9e-15f
#define WINDOW 2e-4f
#define REG_CAP 256u      // per-block flagged-entry slots; E[count]=15, P(>256)~e^-200
#define N_BLOCKS 4096     // 32*32*4 gram blocks

// =================== R8: DIAGNOSTIC ROUND ===================================
// R2-R7: five store-side levers all neutral, gram stuck ~115us (2.3 TB/s
// writes). Gram's counters invisible (harness 1GB fills own top-5). This
// round isolates ONE bit via dur_us arithmetic vs R5's 130.7us baseline:
//   D1 = pure stores in gram's EXACT address pattern (expected S unknown)
//   D2 = pure linear stores, fill-style (calibration, expected ~42us)
// dur ~ 130.7 + S + 42:
//   ~290 -> S~115: write pattern alone is the cost.
//   ~220 -> S~45:  pattern fine; gram cost = read/write interaction/latency.
//   >330 -> even linear writes slow from our kernels.
// Output correctness: the real pipeline runs AFTER the diags and overwrites.
// ============================================================================

// D1: gram's exact store pattern (R5 j-outer variant), value-only.
__global__ __launch_bounds__(256) void store_pattern_kernel(float* __restrict__ out) {
  const int lane = threadIdx.x & 63;
  const int wid = threadIdx.x >> 6;
  const int wm = wid >> 1, wn = wid & 1;
  const int b = blockIdx.z;
  const int row0 = blockIdx.x * 128 + wm * 64;
  const int col0 = blockIdx.y * 128 + wn * 64;
  const int r_in = lane & 15;
  const int cb = (lane >> 4) * 4;
  f32x4 v;
  v[0] = ZEROV; v[1] = ZEROV; v[2] = ZEROV; v[3] = ZEROV;
#pragma unroll 1
  for (int j = 0; j < 4; ++j) {
#pragma unroll
    for (int i = 0; i < 4; ++i) {
      const int row = row0 + i * 16 + r_in;
      const int col = col0 + j * 16 + cb;
      const size_t oi = ((size_t)b << 24) + ((size_t)row << 12) + (size_t)col;
      *(f32x4*)(out + oi) = v;
    }
  }
}

// D2: linear stores, each block owns a contiguous 64KB chunk (fill-style).
__global__ __launch_bounds__(256) void store_linear_kernel(float* __restrict__ out) {
  const size_t base = (size_t)blockIdx.x * 16384 + (size_t)threadIdx.x * 4;
  f32x4 v;
  v[0] = ZEROV; v[1] = ZEROV; v[2] = ZEROV; v[3] = ZEROV;
#pragma unroll 1
  for (int it = 0; it < 16; ++it) {
    *(f32x4*)(out + base + (size_t)it * 1024) = v;
  }
}

// ---------------- Kernel 1: xw = x*w, normalize, split fp32 -> f16 hi/lo ----
__global__ __launch_bounds__(256) void normalize_split_kernel(
    const float* __restrict__ x, const float* __restrict__ w,
    _Float16* __restrict__ hi, _Float16* __restrict__ lo) {
  const int lane = threadIdx.x & 63;
  const int wid = threadIdx.x >> 6;
  const int rg = blockIdx.x * 4 + wid;          // global row 0..16383 (b*4096+n)
  const int n = rg & (N_ROWS - 1);
  const float xv = x[rg * F_DIM + lane];
  const float wv = w[n * F_DIM + lane];
  const float p = xv * wv;
  float s = p * p;
#pragma unroll
  for (int off = 32; off >= 1; off >>= 1) s += __shfl_xor(s, off, 64);
  const float nrm = fmaxf(sqrtf(s), 1e-8f);
  const float xn = p / nrm;
  const _Float16 h = (_Float16)xn;
  const float rem = xn - (float)h;
  hi[rg * F_DIM + lane] = h;
  lo[rg * F_DIM + lane] = (_Float16)rem;
}

// ---------------- Kernel 2: tiled MFMA Gram (R5 variant, unchanged) --------
__global__ __launch_bounds__(256) void gram_kernel(
    const _Float16* __restrict__ hi, const _Float16* __restrict__ lo,
    float* __restrict__ out, unsigned* __restrict__ cnt,
    unsigned* __restrict__ regions) {
  __shared__ unsigned lds_cnt;
  if (threadIdx.x == 0) lds_cnt = 0;
  __syncthreads();

  const int lane = threadIdx.x & 63;
  const int wid = threadIdx.x >> 6;
  const int wm = wid >> 1, wn = wid & 1;
  const int b = blockIdx.z;
  const int row0 = blockIdx.x * 128 + wm * 64;
  const int col0 = blockIdx.y * 128 + wn * 64;
  const int rbase = b * N_ROWS;
  const unsigned bid =
      ((unsigned)blockIdx.z * gridDim.y + blockIdx.y) * gridDim.x + blockIdx.x;
  unsigned* __restrict__ region = regions + (size_t)bid * REG_CAP;

  const int lr = lane & 15;         // fragment row
  const int lk = (lane >> 4) * 8;   // fragment k offset

  // Row-panel (a-side) fragments: load all 16 once, live across the j loop.
  f16x8 ah[2][4], al[2][4];
#pragma unroll
  for (int kf = 0; kf < 2; ++kf)
#pragma unroll
    for (int i = 0; i < 4; ++i) {
      const int ra = (rbase + row0 + i * 16 + lr) * F_DIM + kf * 32 + lk;
      ah[kf][i] = *(const f16x8*)(hi + ra);
      al[kf][i] = *(const f16x8*)(lo + ra);
    }

  const int r_in = lane & 15;        // C/D (transposed): row index within frag
  const int cb = (lane >> 4) * 4;    // col base within frag

#pragma unroll 1
  for (int j = 0; j < 4; ++j) {
    f16x8 bh[2], bl[2];
#pragma unroll
    for (int kf = 0; kf < 2; ++kf) {
      const int rb = (rbase + col0 + j * 16 + lr) * F_DIM + kf * 32 + lk;
      bh[kf] = *(const f16x8*)(hi + rb);
      bl[kf] = *(const f16x8*)(lo + rb);
    }
    f32x4 acc[4] = {};
#pragma unroll
    for (int i = 0; i < 4; ++i) {
#pragma unroll
      for (int kf = 0; kf < 2; ++kf) {
        acc[i] = __builtin_amdgcn_mfma_f32_16x16x32_f16(bh[kf], ah[kf][i], acc[i], 0, 0, 0);
        acc[i] = __builtin_amdgcn_mfma_f32_16x16x32_f16(bh[kf], al[kf][i], acc[i], 0, 0, 0);
        acc[i] = __builtin_amdgcn_mfma_f32_16x16x32_f16(bl[kf], ah[kf][i], acc[i], 0, 0, 0);
      }
    }
#pragma unroll
    for (int i = 0; i < 4; ++i) {
      f32x4 v = acc[i];
      const int row = row0 + i * 16 + r_in;
      const int col = col0 + j * 16 + cb;
      const bool near = fabsf(v[0] - EMPF) < WINDOW || fabsf(v[1] - EMPF) < WINDOW ||
                        fabsf(v[2] - EMPF) < WINDOW || fabsf(v[3] - EMPF) < WINDOW;
      if (__builtin_expect(__any((int)near), 0)) {
#pragma unroll
        for (int r = 0; r < 4; ++r) {
          if (fabsf(v[r] - EMPF) < WINDOW) {
            const unsigned pos = atomicAdd(&lds_cnt, 1u);
            if (pos < REG_CAP)
              region[pos] = ((unsigned)b << 24) | ((unsigned)row << 12) | (unsigned)(col + r);
          }
        }
      }
#pragma unroll
      for (int r = 0; r < 4; ++r) v[r] = (v[r] > EMPF) ? v[r] : ZEROV;
      const size_t oi = ((size_t)b << 24) + ((size_t)row << 12) + (size_t)col;
      *(f32x4*)(out + oi) = v;   // plain store: L2 aggregates full lines
    }
  }

  __syncthreads();
  if (threadIdx.x == 0) cnt[bid] = lds_cnt < REG_CAP ? lds_cnt : REG_CAP;
}

// ---------------- Kernel 3: fp64 exact recompute of near-threshold elems ----
__global__ __launch_bounds__(256) void refine_kernel(
    const float* __restrict__ x, const float* __restrict__ w,
    float* __restrict__ out, const unsigned* __restrict__ cnt,
    const unsigned* __restrict__ regions) {
  const int lane = threadIdx.x & 63;
  const unsigned wg0 = blockIdx.x * (blockDim.x >> 6) + (threadIdx.x >> 6);
  const unsigned nw = gridDim.x * (blockDim.x >> 6);
  for (unsigned rgn = wg0; rgn < N_BLOCKS; rgn += nw) {
    const unsigned count = cnt[rgn];
    const unsigned* __restrict__ region = regions + (size_t)rgn * REG_CAP;
    for (unsigned e = 0; e < count; ++e) {
      const unsigned ent = region[e];
      const int b = (int)(ent >> 24);
      const int i = (int)((ent >> 12) & 4095);
      const int j = (int)(ent & 4095);
      const double wi = (double)w[i * F_DIM + lane];
      const double wj = (double)w[j * F_DIM + lane];
      const double xi = (double)x[(b * N_ROWS + i) * F_DIM + lane];
      const double xj = (double)x[(b * N_ROWS + j) * F_DIM + lane];
      const double pi = xi * wi;
      const double pj = xj * wj;
      double si = pi * pi, sj = pj * pj, sij = pi * pj;
#pragma unroll
      for (int off = 32; off >= 1; off >>= 1) {
        si += __shfl_xor(si, off, 64);
        sj += __shfl_xor(sj, off, 64);
        sij += __shfl_xor(sij, off, 64);
      }
      if (lane == 0) {
        const double ni = fmax(sqrt(si), 1e-8);
        const double nj = fmax(sqrt(sj), 1e-8);
        const double c = sij / (ni * nj);
        const double res = (c > EMPD) ? c : (double)ZEROV;
        out[((size_t)b << 24) + ((size_t)i << 12) + (size_t)j] = (float)res;
      }
    }
  }
}

extern "C" void kernel_launch(void* const* d_in, const int* in_sizes, int n_in,
                              void* d_out, int out_size, void* d_ws, size_t ws_size,
                              hipStream_t stream) {
  const float* x = (const float*)d_in[0];
  const float* w = (const float*)d_in[1];
  float* out = (float*)d_out;

  char* ws = (char*)d_ws;
  _Float16* hi = (_Float16*)ws;                                    // 2 MB
  _Float16* lo = (_Float16*)(ws + (size_t)16384 * 64 * 2);         // 2 MB
  unsigned* cnt = (unsigned*)(ws + (size_t)4 * 1024 * 1024);       // 16 KB
  unsigned* regions = (unsigned*)(ws + (size_t)4 * 1024 * 1024 + 16384); // 4 MB

  // --- diagnostics (results overwritten by the real pipeline below) ---
  store_pattern_kernel<<<dim3(32, 32, 4), 256, 0, stream>>>(out);
  store_linear_kernel<<<4096, 256, 0, stream>>>(out);

  // --- real pipeline (R5, unchanged) ---
  normalize_split_kernel<<<4096, 256, 0, stream>>>(x, w, hi, lo);
  gram_kernel<<<dim3(32, 32, 4), 256, 0, stream>>>(hi, lo, out, cnt, regions);
  refine_kernel<<<1024, 256, 0, stream>>>(x, w, out, cnt, regions);
}

// Round 9
// 175.774 us; speedup vs baseline: 1.3087x; 1.3087x over previous
//
#include <hip/hip_runtime.h>
#include <hip/hip_bf16.h>

typedef _Float16 f16x8 __attribute__((ext_vector_type(8)));
typedef float f32x4 __attribute__((ext_vector_type(4)));

#define N_ROWS 4096
#define F_DIM 64
#define EMPF 0.1f
#define EMPD 0.1
#define ZEROV 9e-15f
#define WINDOW 2e-4f
#define REG_CAP 16u        // per-WAVE slots; E[count]=0.94, Poisson P(>16)~1e-15
#define N_REGIONS 65536    // 64*64*4 blocks * 4 waves

// ---------------- Kernel 1: xw = x*w, normalize, split fp32 -> f16 hi/lo ----
__global__ __launch_bounds__(256) void normalize_split_kernel(
    const float* __restrict__ x, const float* __restrict__ w,
    _Float16* __restrict__ hi, _Float16* __restrict__ lo) {
  const int lane = threadIdx.x & 63;
  const int wid = threadIdx.x >> 6;
  const int rg = blockIdx.x * 4 + wid;          // global row 0..16383 (b*4096+n)
  const int n = rg & (N_ROWS - 1);
  const float xv = x[rg * F_DIM + lane];
  const float wv = w[n * F_DIM + lane];
  const float p = xv * wv;
  float s = p * p;
#pragma unroll
  for (int off = 32; off >= 1; off >>= 1) s += __shfl_xor(s, off, 64);
  const float nrm = fmaxf(sqrtf(s), 1e-8f);
  const float xn = p / nrm;
  const _Float16 h = (_Float16)xn;
  const float rem = xn - (float)h;
  hi[rg * F_DIM + lane] = h;
  lo[rg * F_DIM + lane] = (_Float16)rem;
}

// ---------------- Kernel 2: load-first MFMA Gram ----------------------------
// R8 diagnostic: pure stores in gram's pattern = ~55us @5TB/s, but every gram
// variant = ~100-110us. Theory: vmcnt is SHARED between loads and stores and
// retires OLDEST-FIRST; all prior variants issue next-tile loads AFTER stores,
// so each s_waitcnt before MFMA waits for all older STORES to complete
// (thousands of cycles under write backpressure) -> waves run at store-drain
// pace serially instead of overlapping compute with the write stream.
// R9 fix: 64x64 block tile (32x32/wave). Per wave: ALL 16 loads first ->
// 24 MFMAs -> stores LAST. Nothing after a store consumes vmcnt. No barriers
// (per-wave LDS counters). sched_barrier(0) pins stores below loads.
// cos = hi*hi + hi*lo + lo*hi (lo*lo ~2^-24 dropped); transposed mfma operands
// (R2-verified): out row = row0+i*16+(lane&15), col = col0+j*16+(lane>>4)*4+r.
__global__ __launch_bounds__(256, 4) void gram_kernel(
    const _Float16* __restrict__ hi, const _Float16* __restrict__ lo,
    float* __restrict__ out, unsigned* __restrict__ cnt,
    unsigned* __restrict__ regions) {
  __shared__ unsigned lds_cnt[4];
  const int lane = threadIdx.x & 63;
  const int wid = threadIdx.x >> 6;
  if (lane == 0) lds_cnt[wid] = 0;   // own-wave init; in-order LDS within wave

  const int bz = blockIdx.z;
  const int row0 = blockIdx.x * 64 + (wid >> 1) * 32;
  const int col0 = blockIdx.y * 64 + (wid & 1) * 32;
  const int rbase = bz * N_ROWS;
  const unsigned bid =
      ((unsigned)bz * gridDim.y + blockIdx.y) * gridDim.x + blockIdx.x;
  const unsigned rgn = bid * 4u + (unsigned)wid;
  unsigned* __restrict__ region = regions + (size_t)rgn * REG_CAP;

  const int lr = lane & 15;         // fragment row
  const int lk = (lane >> 4) * 8;   // fragment k offset

  // --- ALL loads up front: no store precedes any load in this wave ---
  f16x8 ah[2][2], al[2][2], bh[2][2], bl[2][2];
#pragma unroll
  for (int g = 0; g < 2; ++g)
#pragma unroll
    for (int kf = 0; kf < 2; ++kf) {
      const int ra = (rbase + row0 + g * 16 + lr) * F_DIM + kf * 32 + lk;
      ah[g][kf] = *(const f16x8*)(hi + ra);
      al[g][kf] = *(const f16x8*)(lo + ra);
      const int rb = (rbase + col0 + g * 16 + lr) * F_DIM + kf * 32 + lk;
      bh[g][kf] = *(const f16x8*)(hi + rb);
      bl[g][kf] = *(const f16x8*)(lo + rb);
    }

  // --- pure compute ---
  f32x4 acc[2][2] = {};
#pragma unroll
  for (int i = 0; i < 2; ++i)
#pragma unroll
    for (int j = 0; j < 2; ++j)
#pragma unroll
      for (int kf = 0; kf < 2; ++kf) {
        acc[i][j] = __builtin_amdgcn_mfma_f32_16x16x32_f16(bh[j][kf], ah[i][kf], acc[i][j], 0, 0, 0);
        acc[i][j] = __builtin_amdgcn_mfma_f32_16x16x32_f16(bh[j][kf], al[i][kf], acc[i][j], 0, 0, 0);
        acc[i][j] = __builtin_amdgcn_mfma_f32_16x16x32_f16(bl[j][kf], ah[i][kf], acc[i][j], 0, 0, 0);
      }

  __builtin_amdgcn_sched_barrier(0);   // stores stay BELOW all loads

  // --- epilogue: threshold + rare flag + 4 f32x4 stores, then nothing ---
  const int r_in = lane & 15;
  const int cb = (lane >> 4) * 4;
#pragma unroll
  for (int i = 0; i < 2; ++i)
#pragma unroll
    for (int j = 0; j < 2; ++j) {
      f32x4 v = acc[i][j];
      const int row = row0 + i * 16 + r_in;
      const int col = col0 + j * 16 + cb;
      const bool near = fabsf(v[0] - EMPF) < WINDOW || fabsf(v[1] - EMPF) < WINDOW ||
                        fabsf(v[2] - EMPF) < WINDOW || fabsf(v[3] - EMPF) < WINDOW;
      if (__builtin_expect(__any((int)near), 0)) {
#pragma unroll
        for (int r = 0; r < 4; ++r) {
          if (fabsf(v[r] - EMPF) < WINDOW) {
            const unsigned pos = atomicAdd(&lds_cnt[wid], 1u);
            if (pos < REG_CAP)
              region[pos] = ((unsigned)bz << 24) | ((unsigned)row << 12) | (unsigned)(col + r);
          }
        }
      }
#pragma unroll
      for (int r = 0; r < 4; ++r) v[r] = (v[r] > EMPF) ? v[r] : ZEROV;
      const size_t oi = ((size_t)bz << 24) + ((size_t)row << 12) + (size_t)col;
      *(f32x4*)(out + oi) = v;
    }

  if (lane == 0) {
    const unsigned c = lds_cnt[wid];
    cnt[rgn] = c < REG_CAP ? c : REG_CAP;
  }
}

// ---------------- Kernel 3: fp64 exact recompute of near-threshold elems ----
// 4096 waves scan 65536 regions (16 each, ~0.94 entries avg per region-hit).
__global__ __launch_bounds__(256) void refine_kernel(
    const float* __restrict__ x, const float* __restrict__ w,
    float* __restrict__ out, const unsigned* __restrict__ cnt,
    const unsigned* __restrict__ regions) {
  const int lane = threadIdx.x & 63;
  const unsigned wg0 = blockIdx.x * (blockDim.x >> 6) + (threadIdx.x >> 6);
  const unsigned nw = gridDim.x * (blockDim.x >> 6);
  for (unsigned rgn = wg0; rgn < N_REGIONS; rgn += nw) {
    const unsigned count = cnt[rgn];
    if (count == 0) continue;
    const unsigned* __restrict__ region = regions + (size_t)rgn * REG_CAP;
    for (unsigned e = 0; e < count && e < REG_CAP; ++e) {
      const unsigned ent = region[e];
      const int b = (int)(ent >> 24);
      const int i = (int)((ent >> 12) & 4095);
      const int j = (int)(ent & 4095);
      const double wi = (double)w[i * F_DIM + lane];
      const double wj = (double)w[j * F_DIM + lane];
      const double xi = (double)x[(b * N_ROWS + i) * F_DIM + lane];
      const double xj = (double)x[(b * N_ROWS + j) * F_DIM + lane];
      const double pi = xi * wi;
      const double pj = xj * wj;
      double si = pi * pi, sj = pj * pj, sij = pi * pj;
#pragma unroll
      for (int off = 32; off >= 1; off >>= 1) {
        si += __shfl_xor(si, off, 64);
        sj += __shfl_xor(sj, off, 64);
        sij += __shfl_xor(sij, off, 64);
      }
      if (lane == 0) {
        const double ni = fmax(sqrt(si), 1e-8);
        const double nj = fmax(sqrt(sj), 1e-8);
        const double c = sij / (ni * nj);
        const double res = (c > EMPD) ? c : (double)ZEROV;
        out[((size_t)b << 24) + ((size_t)i << 12) + (size_t)j] = (float)res;
      }
    }
  }
}

extern "C" void kernel_launch(void* const* d_in, const int* in_sizes, int n_in,
                              void* d_out, int out_size, void* d_ws, size_t ws_size,
                              hipStream_t stream) {
  const float* x = (const float*)d_in[0];
  const float* w = (const float*)d_in[1];
  float* out = (float*)d_out;

  char* ws = (char*)d_ws;
  _Float16* hi = (_Float16*)ws;                                     // 2 MB
  _Float16* lo = (_Float16*)(ws + (size_t)16384 * 64 * 2);          // 2 MB
  unsigned* cnt = (unsigned*)(ws + (size_t)4 * 1024 * 1024);        // 256 KB
  unsigned* regions = (unsigned*)(ws + (size_t)4 * 1024 * 1024 + 262144); // 4 MB

  normalize_split_kernel<<<4096, 256, 0, stream>>>(x, w, hi, lo);
  gram_kernel<<<dim3(64, 64, 4), 256, 0, stream>>>(hi, lo, out, cnt, regions);
  refine_kernel<<<1024, 256, 0, stream>>>(x, w, out, cnt, regions);
}